// Round 13
// baseline (887.123 us; speedup 1.0000x reference)
//
#include <hip/hip_runtime.h>
#include <hip/hip_bf16.h>
#include <cstdint>
#include <cstddef>

#define D_   1024
#define H_   2048
#define G_   4
#define EPG_ 2
#define NE_  8      // G*EPG
#define NH_  16
#define HD_  64
#define L_   4
#define V_   32000
#define NC_  32000
#define B_   2
#define S_   1024
#define T_   2048   // B*S
#define MAXBLK_ 40  // >= sum_e ceil(cnt_e/64) <= 32+8
#define QB_  128    // attention q-tile

typedef __attribute__((__ext_vector_type__(8))) __bf16 bf16x8;
typedef __attribute__((__ext_vector_type__(4))) __bf16 bf16x4;
typedef __attribute__((__ext_vector_type__(4))) float  f32x4;

// async global->LDS, 16B per lane. Dest must be linear (wave base + lane*16).
__device__ __forceinline__ void gl_lds16(const void* g, void* l) {
  __builtin_amdgcn_global_load_lds(
      (const __attribute__((address_space(1))) void*)g,
      (__attribute__((address_space(3))) void*)l, 16, 0, 0);
}

__device__ __forceinline__ float wave_sum(float v) {
  #pragma unroll
  for (int o = 32; o >= 1; o >>= 1) v += __shfl_xor(v, o, 64);
  return v;
}

// ---------------------------------------------------------------- embed
__global__ __launch_bounds__(256) void embed_kernel(const int* __restrict__ x,
    const float* __restrict__ tok, const float* __restrict__ pos,
    float* __restrict__ h) {
  int t = blockIdx.x;
  int tid = threadIdx.x;
  int token = x[t];
  int s = t & (S_ - 1);
  float4 tv = *(const float4*)(tok + (size_t)token * D_ + tid * 4);
  float4 pv = *(const float4*)(pos + (size_t)s * D_ + tid * 4);
  float4 r;
  r.x = tv.x + pv.x; r.y = tv.y + pv.y; r.z = tv.z + pv.z; r.w = tv.w + pv.w;
  *(float4*)(h + (size_t)t * D_ + tid * 4) = r;
}

// ---------------------------------------------------------------- layernorm (block per token)
__device__ __forceinline__ float block_sum256(float v, float* sbuf) {
  v = wave_sum(v);
  int tid = threadIdx.x;
  if ((tid & 63) == 0) sbuf[tid >> 6] = v;
  __syncthreads();
  float r = sbuf[0] + sbuf[1] + sbuf[2] + sbuf[3];
  __syncthreads();
  return r;
}

template<bool F32OUT, bool BFOUT>
__global__ __launch_bounds__(256) void ln_kernel(const float* __restrict__ X,
    const float* __restrict__ w, const float* __restrict__ b,
    float* __restrict__ Yf, __bf16* __restrict__ Yb) {
  __shared__ float sbuf[4];
  int t = blockIdx.x, tid = threadIdx.x;
  const float* xr = X + (size_t)t * D_;
  float4 v = *(const float4*)(xr + tid * 4);
  float sum = v.x + v.y + v.z + v.w;
  float m = block_sum256(sum, sbuf) * (1.0f / D_);
  float dx = v.x - m, dy = v.y - m, dz = v.z - m, dw = v.w - m;
  float vs = dx * dx + dy * dy + dz * dz + dw * dw;
  float var = block_sum256(vs, sbuf) * (1.0f / D_);
  float rs = rsqrtf(var + 1e-5f);
  float4 wv = *(const float4*)(w + tid * 4);
  float4 bv = *(const float4*)(b + tid * 4);
  float4 o;
  o.x = dx * rs * wv.x + bv.x;
  o.y = dy * rs * wv.y + bv.y;
  o.z = dz * rs * wv.z + bv.z;
  o.w = dw * rs * wv.w + bv.w;
  if (F32OUT) *(float4*)(Yf + (size_t)t * D_ + tid * 4) = o;
  if (BFOUT) {
    bf16x4 ob = {(__bf16)o.x, (__bf16)o.y, (__bf16)o.z, (__bf16)o.w};
    *(bf16x4*)(Yb + (size_t)t * D_ + tid * 4) = ob;
  }
}

// ---------------------------------------------------------------- fused ln2 + routing
__global__ __launch_bounds__(256) void ln_route_kernel(const float* __restrict__ X,
    const float* __restrict__ lw, const float* __restrict__ lb,
    const float* __restrict__ gw, const float* __restrict__ gb,
    const float* __restrict__ ew, const float* __restrict__ eb,
    __bf16* __restrict__ Yb, int* __restrict__ eidx, float* __restrict__ gate) {
  int wv = threadIdx.x >> 6, lane = threadIdx.x & 63;
  int t = blockIdx.x * 4 + wv;
  const float* xr = X + (size_t)t * D_;
  float4 xv[4];
  #pragma unroll
  for (int k = 0; k < 4; k++) xv[k] = *(const float4*)(xr + lane * 4 + k * 256);
  float s = 0.f;
  #pragma unroll
  for (int k = 0; k < 4; k++) s += xv[k].x + xv[k].y + xv[k].z + xv[k].w;
  float m = wave_sum(s) * (1.0f / D_);
  float vs = 0.f;
  #pragma unroll
  for (int k = 0; k < 4; k++) {
    float a = xv[k].x - m, b2 = xv[k].y - m, c = xv[k].z - m, d = xv[k].w - m;
    vs += a * a + b2 * b2 + c * c + d * d;
  }
  float rs = rsqrtf(wave_sum(vs) * (1.0f / D_) + 1e-5f);
  float y[4][4];
  #pragma unroll
  for (int k = 0; k < 4; k++) {
    int d0 = lane * 4 + k * 256;
    float4 wv4 = *(const float4*)(lw + d0);
    float4 bv4 = *(const float4*)(lb + d0);
    y[k][0] = (xv[k].x - m) * rs * wv4.x + bv4.x;
    y[k][1] = (xv[k].y - m) * rs * wv4.y + bv4.y;
    y[k][2] = (xv[k].z - m) * rs * wv4.z + bv4.z;
    y[k][3] = (xv[k].w - m) * rs * wv4.w + bv4.w;
    bf16x4 ob = {(__bf16)y[k][0], (__bf16)y[k][1], (__bf16)y[k][2], (__bf16)y[k][3]};
    *(bf16x4*)(Yb + (size_t)t * D_ + d0) = ob;
  }
  float g0 = 0, g1 = 0, g2 = 0, g3 = 0;
  #pragma unroll
  for (int k = 0; k < 4; k++)
    #pragma unroll
    for (int j = 0; j < 4; j++) {
      int d = lane * 4 + k * 256 + j;
      float4 gv = *(const float4*)(gw + (size_t)d * G_);
      float yv = y[k][j];
      g0 += yv * gv.x; g1 += yv * gv.y; g2 += yv * gv.z; g3 += yv * gv.w;
    }
  g0 = wave_sum(g0) + gb[0];
  g1 = wave_sum(g1) + gb[1];
  g2 = wave_sum(g2) + gb[2];
  g3 = wave_sum(g3) + gb[3];
  float mx = fmaxf(fmaxf(g0, g1), fmaxf(g2, g3));
  float p0 = __expf(g0 - mx), p1 = __expf(g1 - mx), p2 = __expf(g2 - mx), p3 = __expf(g3 - mx);
  float psum = p0 + p1 + p2 + p3;
  int gidx = 0; float best = g0;
  if (g1 > best) { best = g1; gidx = 1; }
  if (g2 > best) { best = g2; gidx = 2; }
  if (g3 > best) { best = g3; gidx = 3; }
  float gpsel = ((gidx == 0) ? p0 : (gidx == 1) ? p1 : (gidx == 2) ? p2 : p3) / psum;
  const float* ewg = ew + (size_t)gidx * D_ * EPG_;
  float e0 = 0, e1 = 0;
  #pragma unroll
  for (int k = 0; k < 4; k++)
    #pragma unroll
    for (int j = 0; j < 4; j++) {
      int d = lane * 4 + k * 256 + j;
      float2 ev = *(const float2*)(ewg + (size_t)d * EPG_);
      e0 += y[k][j] * ev.x; e1 += y[k][j] * ev.y;
    }
  e0 = wave_sum(e0) + eb[gidx * EPG_ + 0];
  e1 = wave_sum(e1) + eb[gidx * EPG_ + 1];
  float em = fmaxf(e0, e1);
  float q0 = __expf(e0 - em), q1 = __expf(e1 - em);
  int ei = (e1 > e0) ? 1 : 0;
  float epsel = ((ei == 0) ? q0 : q1) / (q0 + q1);
  if (lane == 0) {
    eidx[t] = gidx * EPG_ + ei;
    gate[t] = gpsel * epsel;
  }
}

// ---------------------------------------------------------------- finalize (64-row block list)
__global__ __launch_bounds__(256) void finalize_kernel(const int* __restrict__ eidx,
    int* __restrict__ counts, int* __restrict__ offs, int* __restrict__ tlist,
    int* __restrict__ blk) {
  __shared__ int hist[256][NE_];
  __shared__ int eoff[NE_];
  int tid = threadIdx.x;
  int loc[NE_];
  #pragma unroll
  for (int e = 0; e < NE_; e++) loc[e] = 0;
  int te[8];
  #pragma unroll
  for (int i = 0; i < 8; i++) { te[i] = eidx[tid * 8 + i]; loc[te[i]]++; }
  #pragma unroll
  for (int e = 0; e < NE_; e++) hist[tid][e] = loc[e];
  __syncthreads();
  for (int off = 1; off < 256; off <<= 1) {
    int v[NE_];
    #pragma unroll
    for (int e = 0; e < NE_; e++) v[e] = (tid >= off) ? hist[tid - off][e] : 0;
    __syncthreads();
    #pragma unroll
    for (int e = 0; e < NE_; e++) hist[tid][e] += v[e];
    __syncthreads();
  }
  if (tid == 0) {
    int acc = 0, nb = 0;
    for (int e = 0; e < NE_; e++) {
      int c = hist[255][e];
      eoff[e] = acc; counts[e] = c; offs[e] = acc; acc += c;
      for (int mt = 0; mt * 64 < c; mt++) blk[nb++] = e | (mt << 8);
    }
    for (; nb < MAXBLK_; nb++) blk[nb] = -1;
  }
  __syncthreads();
  int run[NE_];
  #pragma unroll
  for (int e = 0; e < NE_; e++) run[e] = eoff[e] + hist[tid][e] - loc[e];
  #pragma unroll
  for (int i = 0; i < 8; i++) {
    int e = te[i];
    tlist[run[e]++] = tid * 8 + i;
  }
}

// ---------------------------------------------------------------- bf16 MFMA GEMM (64-row tile, 2x2 waves)
// MODE 0: Cb = acc+bias (bf16)                       [qkv]
// MODE 1: Cf += acc+bias (f32 residual)              [out-proj]
// MODE 2: gather rows via tlist; Cb[compact] = relu  [moe w1]
// MODE 3: linear rows from compact; scatter to h     [moe w2]
template<int MODE, int NF, bool KN>
__global__ __launch_bounds__(256, 3) void gemm_mfma(
    const __bf16* __restrict__ A, const float* __restrict__ W,
    const float* __restrict__ bias, float* __restrict__ Cf,
    __bf16* __restrict__ Cb, const int* __restrict__ tlist,
    const int* __restrict__ offs, const int* __restrict__ counts,
    const float* __restrict__ gate, const int* __restrict__ blk,
    int N, int K) {
  __shared__ __bf16 As[2][64 * 64];
  __shared__ __bf16 Bs[2][NF * 32 * 64];
  int e = 0, mt = blockIdx.y, cnt = T_;
  if (MODE >= 2) {
    int bv = blk[blockIdx.y];
    if (bv < 0) return;
    e = bv & 255; mt = bv >> 8;
    cnt = counts[e];
  }
  int row0 = mt * 64;
  int lbase = (MODE >= 2) ? offs[e] : 0;
  int col0 = blockIdx.x * (NF * 32);
  const float* Wp = W + (size_t)e * N * K;
  const float* bp = bias + (size_t)e * N;
  int tid = threadIdx.x;
  int w = tid >> 6, lane = tid & 63, lq = lane & 15, lg = lane >> 4;
  int wr = w >> 1, wc = w & 1;

  const __bf16* asrc[2];
  #pragma unroll
  for (int it = 0; it < 2; it++) {
    int v = it * 256 + tid;
    int r = v >> 3, u = v & 7;
    int gr = row0 + r;
    long rowidx;
    if (MODE == 2) rowidx = tlist[lbase + ((gr < cnt) ? gr : cnt - 1)];
    else if (MODE == 3) rowidx = lbase + ((gr < cnt) ? gr : cnt - 1);
    else rowidx = gr;
    asrc[it] = A + (size_t)rowidx * K + (u ^ (r & 7)) * 8;
  }

  // --- B staging descriptors ---
  const float* bsrcNK[NF];
  int bdstNK[NF];
  const float* bbase = nullptr;   // KN vector-load base
  int wdst[NF];                   // KN write offsets (halfwords)
  int nq = tid & 31, kg = tid >> 5;   // KN mapping: kg in 0..7 (k-octet)
  if (KN) {
    bbase = Wp + (size_t)(kg * 8) * N + col0 + nq * NF;
    #pragma unroll
    for (int jj = 0; jj < NF; jj++) {
      int n = nq * NF + jj;
      int slot = (kg ^ (n & 7) ^ ((n >> 3) & 7)) & 7;
      wdst[jj] = n * 64 + slot * 8;
    }
  } else {
    #pragma unroll
    for (int it = 0; it < NF; it++) {
      int v = it * 256 + tid;
      int n = v >> 3, u = v & 7;
      bsrcNK[it] = Wp + (size_t)(col0 + n) * K + u * 8;
      bdstNK[it] = n * 64 + ((u ^ (n & 7) ^ ((n >> 3) & 7)) & 7) * 8;
    }
  }

  float brp[NF * 8];
  f32x4 acc[2][NF] = {};

  auto loadB = [&](int k0) {
    if (KN) {
      #pragma unroll
      for (int j = 0; j < 8; j++) {
        if (NF == 4) {
          float4 f = *(const float4*)(bbase + (size_t)(k0 + j) * N);
          brp[j * 4 + 0] = f.x; brp[j * 4 + 1] = f.y;
          brp[j * 4 + 2] = f.z; brp[j * 4 + 3] = f.w;
        } else {
          float2 f = *(const float2*)(bbase + (size_t)(k0 + j) * N);
          brp[j * 2 + 0] = f.x; brp[j * 2 + 1] = f.y;
        }
      }
    } else {
      #pragma unroll
      for (int it = 0; it < NF; it++) {
        float4 f0 = *(const float4*)(bsrcNK[it] + k0);
        float4 f1 = *(const float4*)(bsrcNK[it] + k0 + 4);
        brp[it * 8 + 0] = f0.x; brp[it * 8 + 1] = f0.y;
        brp[it * 8 + 2] = f0.z; brp[it * 8 + 3] = f0.w;
        brp[it * 8 + 4] = f1.x; brp[it * 8 + 5] = f1.y;
        brp[it * 8 + 6] = f1.z; brp[it * 8 + 7] = f1.w;
      }
    }
  };
  auto writeB = [&](int buf) {
    if (KN) {
      #pragma unroll
      for (int jj = 0; jj < NF; jj++) {
        bf16x8 bb = {(__bf16)brp[0 * NF + jj], (__bf16)brp[1 * NF + jj],
                     (__bf16)brp[2 * NF + jj], (__bf16)brp[3 * NF + jj],
                     (__bf16)brp[4 * NF + jj], (__bf16)brp[5 * NF + jj],
                     (__bf16)brp[6 * NF + jj], (__bf16)brp[7 * NF + jj]};
        *(bf16x8*)&Bs[buf][wdst[jj]] = bb;
      }
    } else {
      #pragma unroll
      for (int it = 0; it < NF; it++) {
        bf16x8 bb = {(__bf16)brp[it * 8 + 0], (__bf16)brp[it * 8 + 1],
                     (__bf16)brp[it * 8 + 2], (__bf16)brp[it * 8 + 3],
                     (__bf16)brp[it * 8 + 4], (__bf16)brp[it * 8 + 5],
                     (__bf16)brp[it * 8 + 6], (__bf16)brp[it * 8 + 7]};
        *(bf16x8*)&Bs[buf][bdstNK[it]] = bb;
      }
    }
  };
  auto stageA = [&](int buf, int k0) {
    #pragma unroll
    for (int it = 0; it < 2; it++)
      gl_lds16(asrc[it] + k0, &As[buf][(it * 256 + tid) * 8]);
  };
  auto mfmaPhase = [&](int buf) {
    __builtin_amdgcn_s_setprio(1);
    #pragma unroll
    for (int kk = 0; kk < 2; kk++) {
      bf16x8 a[2], b[NF];
      int usa = ((lg + kk * 4) ^ (lq & 7)) * 8;
      #pragma unroll
      for (int fi = 0; fi < 2; fi++)
        a[fi] = *(const bf16x8*)&As[buf][(wr * 32 + fi * 16 + lq) * 64 + usa];
      #pragma unroll
      for (int fj = 0; fj < NF; fj++) {
        int brow = wc * (NF * 16) + fj * 16 + lq;
        int usb = (((lg + kk * 4) ^ (brow & 7) ^ ((brow >> 3) & 7)) & 7) * 8;
        b[fj] = *(const bf16x8*)&Bs[buf][brow * 64 + usb];
      }
      #pragma unroll
      for (int fi = 0; fi < 2; fi++)
        #pragma unroll
        for (int fj = 0; fj < NF; fj++)
          acc[fi][fj] = __builtin_amdgcn_mfma_f32_16x16x32_bf16(a[fi], b[fj], acc[fi][fj], 0, 0, 0);
    }
    __builtin_amdgcn_s_setprio(0);
  };

  loadB(0);
  stageA(0, 0);
  writeB(0);
  __syncthreads();

  int buf = 0;
  for (int k0 = 0; k0 < K; k0 += 64) {
    int nk = k0 + 64;
    if (nk < K) {
      stageA(buf ^ 1, nk);
      loadB(nk);
    }
    mfmaPhase(buf);
    if (nk < K) writeB(buf ^ 1);
    __syncthreads();
    buf ^= 1;
  }

  #pragma unroll
  for (int fi = 0; fi < 2; fi++) {
    #pragma unroll
    for (int v = 0; v < 4; v++) {
      int r = row0 + wr * 32 + fi * 16 + lg * 4 + v;
      long orow;
      float gv = 1.f;
      if (MODE >= 2) {
        if (r >= cnt) continue;
        if (MODE == 2) orow = lbase + r;
        else { orow = tlist[lbase + r]; gv = gate[orow]; }
      } else {
        orow = r;
      }
      #pragma unroll
      for (int fj = 0; fj < NF; fj++) {
        int c = col0 + wc * (NF * 16) + fj * 16 + lq;
        float val = acc[fi][fj][v] + bp[c];
        if (MODE == 0)      Cb[orow * N + c] = (__bf16)val;
        else if (MODE == 1) Cf[orow * N + c] += val;
        else if (MODE == 2) Cb[orow * N + c] = (__bf16)fmaxf(val, 0.f);
        else                Cf[orow * N + c] += gv * val;
      }
    }
  }
}

// ---------------------------------------------------------------- flash attention, bf16 MFMA
// QB_=128, 512 thr = 8 waves. K/V double-buffered: stage(kt+1) issued before
// compute(kt) -> load latency hides under MFMA+softmax; 1 barrier per tile.
#define SC_LOG2 0.18033688011112042f   // (1/sqrt(64)) * log2(e)
__global__ __launch_bounds__(512) void attn_mfma_kernel(const __bf16* __restrict__ qkv,
                                                        __bf16* __restrict__ out) {
  __shared__ __bf16 Ks[2][64][72];
  __shared__ __bf16 Vt[2][64][72];  // [d][kv^swz]
  __shared__ __bf16 Ps[QB_][72];    // wave-private 16-row slabs
  int tid = threadIdx.x;
  int w = tid >> 6, lane = tid & 63, lq = lane & 15, lg = lane >> 4;
  int qt = (S_ / QB_ - 1) - blockIdx.x;   // heaviest first
  int b = blockIdx.y >> 4, hh = blockIdx.y & 15;
  const __bf16* qbase = qkv + (size_t)b * S_ * 3 * D_ + hh * HD_;

  bf16x8 qa[2];
  {
    const __bf16* qp = qbase + (size_t)(qt * QB_ + w * 16 + lq) * 3 * D_ + lg * 8;
    qa[0] = *(const bf16x8*)qp;
    qa[1] = *(const bf16x8*)(qp + 32);
  }

  f32x4 o[4] = {};
  float m_[4] = {-1e30f, -1e30f, -1e30f, -1e30f};
  float l_[4] = {0.f, 0.f, 0.f, 0.f};

  int rowmin = qt * QB_ + w * 16;       // first q-row this wave owns
  int srow = tid >> 3, sc8 = tid & 7;   // staging coords (512 thr cover 64x8)
  int nkt = qt * 2 + 2;

  auto stage = [&](int sb, int kt) {
    const __bf16* kp = qbase + (size_t)(kt * 64 + srow) * 3 * D_ + D_ + sc8 * 8;
    *(bf16x8*)&Ks[sb][srow][sc8 * 8] = *(const bf16x8*)kp;
    bf16x8 vv = *(const bf16x8*)(kp + D_);
    int cs = srow ^ (sc8 << 3);
    #pragma unroll
    for (int j = 0; j < 8; j++) Vt[sb][sc8 * 8 + j][cs] = vv[j];
  };

  stage(0, 0);
  __syncthreads();

  int buf = 0;
  for (int kt = 0; kt < nkt; kt++) {
    if (kt + 1 < nkt) stage(buf ^ 1, kt + 1);   // issue-early; writes land pre-barrier

    if (kt * 64 <= rowmin + 15) {       // wave active for this tile
      f32x4 s[4] = {};
      #pragma unroll
      for (int kk = 0; kk < 2; kk++)
        #pragma unroll
        for (int fc = 0; fc < 4; fc++) {
          bf16x8 kf = *(const bf16x8*)&Ks[buf][fc * 16 + lq][lg * 8 + kk * 32];
          s[fc] = __builtin_amdgcn_mfma_f32_16x16x32_bf16(qa[kk], kf, s[fc], 0, 0, 0);
        }

      bool need_mask = (kt * 64 + 63 > rowmin);
      #pragma unroll
      for (int fc = 0; fc < 4; fc++)
        #pragma unroll
        for (int v = 0; v < 4; v++) {
          float sv = s[fc][v] * SC_LOG2;
          if (need_mask && (kt * 64 + fc * 16 + lq) > (rowmin + lg * 4 + v)) sv = -1e30f;
          s[fc][v] = sv;
        }

      #pragma unroll
      for (int v = 0; v < 4; v++) {
        float rm = fmaxf(fmaxf(s[0][v], s[1][v]), fmaxf(s[2][v], s[3][v]));
        #pragma unroll
        for (int o2 = 8; o2 >= 1; o2 >>= 1) rm = fmaxf(rm, __shfl_xor(rm, o2, 64));
        if (rm > m_[v]) {   // rescale only when max grows (exact skip otherwise)
          float cc = exp2f(m_[v] - rm);
          m_[v] = rm;
          l_[v] *= cc;
          o[0][v] *= cc; o[1][v] *= cc; o[2][v] *= cc; o[3][v] *= cc;
        }
        float rs = 0.f;
        #pragma unroll
        for (int fc = 0; fc < 4; fc++) {
          float p = exp2f(s[fc][v] - m_[v]);
          s[fc][v] = p; rs += p;
        }
        l_[v] += rs;
        #pragma unroll
        for (int fc = 0; fc < 4; fc++)
          Ps[w * 16 + lg * 4 + v][fc * 16 + lq] = (__bf16)s[fc][v];
      }
      asm volatile("" ::: "memory");   // same-wave LDS FIFO: writes before reads

      #pragma unroll
      for (int kk = 0; kk < 2; kk++) {
        bf16x8 pa = *(const bf16x8*)&Ps[w * 16 + lq][lg * 8 + kk * 32];
        #pragma unroll
        for (int dc = 0; dc < 4; dc++) {
          int d = dc * 16 + lq;
          int col = (lg * 8 + kk * 32) ^ ((d >> 3) << 3);
          bf16x8 vb = *(const bf16x8*)&Vt[buf][d][col];
          o[dc] = __builtin_amdgcn_mfma_f32_16x16x32_bf16(pa, vb, o[dc], 0, 0, 0);
        }
      }
    }
    __syncthreads();   // joint: stage(buf^1) writes done AND compute(buf) reads done
    buf ^= 1;
  }

  #pragma unroll
  for (int v = 0; v < 4; v++) {
    float ls = l_[v];
    #pragma unroll
    for (int o2 = 8; o2 >= 1; o2 >>= 1) ls += __shfl_xor(ls, o2, 64);
    float inv = 1.0f / ls;
    int row = rowmin + lg * 4 + v;
    __bf16* op = out + ((size_t)b * S_ + row) * D_ + hh * HD_;
    #pragma unroll
    for (int dc = 0; dc < 4; dc++)
      op[dc * 16 + lq] = (__bf16)(o[dc][v] * inv);
  }
}

// ---------------------------------------------------------------- final mean + head (fp32)
__global__ __launch_bounds__(256) void mean_part_kernel(const float* __restrict__ X,
                                                        float* __restrict__ part) {
  int bd = blockIdx.x * 256 + threadIdx.x;
  int chunk = blockIdx.y;
  int b = bd >> 10, d = bd & 1023;
  float s = 0.f;
  #pragma unroll 4
  for (int i = 0; i < 64; i++) {
    int sidx = chunk * 64 + i;
    s += X[((size_t)b * S_ + sidx) * D_ + d];
  }
  part[chunk * T_ + bd] = s;
}

__global__ __launch_bounds__(256) void mean_final_kernel(const float* __restrict__ part,
                                                         float* __restrict__ hm) {
  int bd = blockIdx.x * 256 + threadIdx.x;
  float s = 0.f;
  #pragma unroll
  for (int c = 0; c < 16; c++) s += part[c * T_ + bd];
  hm[bd] = s * (1.0f / S_);
}

__global__ __launch_bounds__(256) void head_kernel(const float* __restrict__ hm,
    const float* __restrict__ hw, const float* __restrict__ hb,
    float* __restrict__ out) {
  int w = threadIdx.x >> 6;
  int lane = threadIdx.x & 63;
  int c = blockIdx.x * 4 + w;
  const float* row = hw + (size_t)c * D_;
  float acc0 = 0.f, acc1 = 0.f;
  #pragma unroll
  for (int k = 0; k < 4; k++) {
    int d = lane * 4 + k * 256;
    float4 wv = *(const float4*)(row + d);
    float4 h0 = *(const float4*)(hm + d);
    float4 h1 = *(const float4*)(hm + D_ + d);
    acc0 += wv.x * h0.x + wv.y * h0.y + wv.z * h0.z + wv.w * h0.w;
    acc1 += wv.x * h1.x + wv.y * h1.y + wv.z * h1.z + wv.w * h1.w;
  }
  #pragma unroll
  for (int o = 32; o >= 1; o >>= 1) {
    acc0 += __shfl_xor(acc0, o, 64);
    acc1 += __shfl_xor(acc1, o, 64);
  }
  if (lane == 0) {
    float bias = hb[c];
    out[c] = acc0 + bias;
    out[NC_ + c] = acc1 + bias;
  }
}

// ---------------------------------------------------------------- host launch
extern "C" void kernel_launch(void* const* d_in, const int* in_sizes, int n_in,
                              void* d_out, int out_size, void* d_ws, size_t ws_size,
                              hipStream_t stream) {
  const int*   x        = (const int*)d_in[0];
  const float* tok_emb  = (const float*)d_in[1];
  const float* pos_emb  = (const float*)d_in[2];
  const float* in_proj_w= (const float*)d_in[3];
  const float* in_proj_b= (const float*)d_in[4];
  const float* out_w    = (const float*)d_in[5];
  const float* out_b    = (const float*)d_in[6];
  const float* ln1_w    = (const float*)d_in[7];
  const float* ln1_b    = (const float*)d_in[8];
  const float* ln2_w    = (const float*)d_in[9];
  const float* ln2_b    = (const float*)d_in[10];
  const float* gr_w     = (const float*)d_in[11];
  const float* gr_b     = (const float*)d_in[12];
  const float* er_w     = (const float*)d_in[13];
  const float* er_b     = (const float*)d_in[14];
  const float* w1       = (const float*)d_in[15];
  const float* b1       = (const float*)d_in[16];
  const float* w2       = (const float*)d_in[17];
  const float* b2       = (const float*)d_in[18];
  const float* lnf_w    = (const float*)d_in[19];
  const float* lnf_b    = (const float*)d_in[20];
  const float* head_w   = (const float*)d_in[21];
  const float* head_b   = (const float*)d_in[22];

  char* wp = (char*)d_ws;
  auto carve = [&](size_t bytes) -> char* {
    char* p = wp;
    wp += (bytes + 255) & ~(size_t)255;
    return p;
  };
  float*  h      = (float*)carve((size_t)T_ * D_ * 4);
  float*  x1     = (float*)carve((size_t)T_ * D_ * 4);
  __bf16* x1b    = (__bf16*)carve((size_t)T_ * D_ * 2);
  __bf16* qkvb   = (__bf16*)carve((size_t)T_ * 3 * D_ * 2);
  __bf16* attnb  = (__bf16*)carve((size_t)T_ * D_ * 2);
  __bf16* hmidb  = (__bf16*)carve((size_t)T_ * H_ * 2);
  float*  part   = (float*)carve((size_t)16 * T_ * 4);
  float*  hm     = (float*)carve((size_t)B_ * D_ * 4);
  float*  gate   = (float*)carve((size_t)T_ * 4);
  int*    eidx   = (int*)carve((size_t)T_ * 4);
  int*    tlist  = (int*)carve((size_t)T_ * 4);
  int*    counts = (int*)carve(64);
  int*    offs   = (int*)carve(64);
  int*    blk    = (int*)carve(MAXBLK_ * 4);

  embed_kernel<<<T_, 256, 0, stream>>>(x, tok_emb, pos_emb, h);

  for (int l = 0; l < L_; l++) {
    // ---- attention half
    ln_kernel<false, true><<<T_, 256, 0, stream>>>(h, ln1_w + l * D_, ln1_b + l * D_,
                                                   nullptr, x1b);
    gemm_mfma<0, 2, false><<<dim3(48, 32, 1), 256, 0, stream>>>(
        x1b, in_proj_w + (size_t)l * 3 * D_ * D_, in_proj_b + (size_t)l * 3 * D_,
        nullptr, qkvb, nullptr, nullptr, nullptr, nullptr, nullptr, 3 * D_, D_);
    attn_mfma_kernel<<<dim3(S_ / QB_, B_ * NH_), 512, 0, stream>>>(qkvb, attnb);
    gemm_mfma<1, 2, false><<<dim3(16, 32, 1), 256, 0, stream>>>(
        attnb, out_w + (size_t)l * D_ * D_, out_b + (size_t)l * D_, h, nullptr,
        nullptr, nullptr, nullptr, nullptr, nullptr, D_, D_);

    // ---- MoE half (fused ln2 + route)
    ln_route_kernel<<<T_ / 4, 256, 0, stream>>>(h,
        ln2_w + l * D_, ln2_b + l * D_,
        gr_w + (size_t)l * D_ * G_, gr_b + (size_t)l * G_,
        er_w + (size_t)l * G_ * D_ * EPG_, er_b + (size_t)l * G_ * EPG_,
        x1b, eidx, gate);
    finalize_kernel<<<1, 256, 0, stream>>>(eidx, counts, offs, tlist, blk);

    gemm_mfma<2, 2, true><<<dim3(H_ / 64, MAXBLK_, 1), 256, 0, stream>>>(
        x1b, w1 + (size_t)l * NE_ * D_ * H_, b1 + (size_t)l * NE_ * H_, nullptr, hmidb,
        tlist, offs, counts, nullptr, blk, H_, D_);
    gemm_mfma<3, 2, true><<<dim3(D_ / 64, MAXBLK_, 1), 256, 0, stream>>>(
        hmidb, w2 + (size_t)l * NE_ * H_ * D_, b2 + (size_t)l * NE_ * D_, h, nullptr,
        tlist, offs, counts, gate, blk, D_, H_);
  }

  ln_kernel<true, false><<<T_, 256, 0, stream>>>(h, lnf_w, lnf_b, x1, nullptr);
  mean_part_kernel<<<dim3(B_ * D_ / 256, 16), 256, 0, stream>>>(x1, part);
  mean_final_kernel<<<B_ * D_ / 256, 256, 0, stream>>>(part, hm);
  head_kernel<<<NC_ / 4, 256, 0, stream>>>(hm, head_w, head_b, (float*)d_out);
}

// Round 14
// 850.280 us; speedup vs baseline: 1.0433x; 1.0433x over previous
//
#include <hip/hip_runtime.h>
#include <hip/hip_bf16.h>
#include <cstdint>
#include <cstddef>

#define D_   1024
#define H_   2048
#define G_   4
#define EPG_ 2
#define NE_  8      // G*EPG
#define NH_  16
#define HD_  64
#define L_   4
#define V_   32000
#define NC_  32000
#define B_   2
#define S_   1024
#define T_   2048   // B*S
#define MAXBLK_ 40  // >= sum_e ceil(cnt_e/64) <= 32+8
#define QB_  128    // attention q-tile

typedef __attribute__((__ext_vector_type__(8))) __bf16 bf16x8;
typedef __attribute__((__ext_vector_type__(4))) __bf16 bf16x4;
typedef __attribute__((__ext_vector_type__(4))) float  f32x4;

// async global->LDS, 16B per lane. Dest must be linear (wave base + lane*16).
__device__ __forceinline__ void gl_lds16(const void* g, void* l) {
  __builtin_amdgcn_global_load_lds(
      (const __attribute__((address_space(1))) void*)g,
      (__attribute__((address_space(3))) void*)l, 16, 0, 0);
}

__device__ __forceinline__ float wave_sum(float v) {
  #pragma unroll
  for (int o = 32; o >= 1; o >>= 1) v += __shfl_xor(v, o, 64);
  return v;
}

// ---------------------------------------------------------------- embed
__global__ __launch_bounds__(256) void embed_kernel(const int* __restrict__ x,
    const float* __restrict__ tok, const float* __restrict__ pos,
    float* __restrict__ h) {
  int t = blockIdx.x;
  int tid = threadIdx.x;
  int token = x[t];
  int s = t & (S_ - 1);
  float4 tv = *(const float4*)(tok + (size_t)token * D_ + tid * 4);
  float4 pv = *(const float4*)(pos + (size_t)s * D_ + tid * 4);
  float4 r;
  r.x = tv.x + pv.x; r.y = tv.y + pv.y; r.z = tv.z + pv.z; r.w = tv.w + pv.w;
  *(float4*)(h + (size_t)t * D_ + tid * 4) = r;
}

// ---------------------------------------------------------------- layernorm (block per token)
__device__ __forceinline__ float block_sum256(float v, float* sbuf) {
  v = wave_sum(v);
  int tid = threadIdx.x;
  if ((tid & 63) == 0) sbuf[tid >> 6] = v;
  __syncthreads();
  float r = sbuf[0] + sbuf[1] + sbuf[2] + sbuf[3];
  __syncthreads();
  return r;
}

template<bool F32OUT, bool BFOUT>
__global__ __launch_bounds__(256) void ln_kernel(const float* __restrict__ X,
    const float* __restrict__ w, const float* __restrict__ b,
    float* __restrict__ Yf, __bf16* __restrict__ Yb) {
  __shared__ float sbuf[4];
  int t = blockIdx.x, tid = threadIdx.x;
  const float* xr = X + (size_t)t * D_;
  float4 v = *(const float4*)(xr + tid * 4);
  float sum = v.x + v.y + v.z + v.w;
  float m = block_sum256(sum, sbuf) * (1.0f / D_);
  float dx = v.x - m, dy = v.y - m, dz = v.z - m, dw = v.w - m;
  float vs = dx * dx + dy * dy + dz * dz + dw * dw;
  float var = block_sum256(vs, sbuf) * (1.0f / D_);
  float rs = rsqrtf(var + 1e-5f);
  float4 wv = *(const float4*)(w + tid * 4);
  float4 bv = *(const float4*)(b + tid * 4);
  float4 o;
  o.x = dx * rs * wv.x + bv.x;
  o.y = dy * rs * wv.y + bv.y;
  o.z = dz * rs * wv.z + bv.z;
  o.w = dw * rs * wv.w + bv.w;
  if (F32OUT) *(float4*)(Yf + (size_t)t * D_ + tid * 4) = o;
  if (BFOUT) {
    bf16x4 ob = {(__bf16)o.x, (__bf16)o.y, (__bf16)o.z, (__bf16)o.w};
    *(bf16x4*)(Yb + (size_t)t * D_ + tid * 4) = ob;
  }
}

// ---------------------------------------------------------------- fused ln2 + routing
__global__ __launch_bounds__(256) void ln_route_kernel(const float* __restrict__ X,
    const float* __restrict__ lw, const float* __restrict__ lb,
    const float* __restrict__ gw, const float* __restrict__ gb,
    const float* __restrict__ ew, const float* __restrict__ eb,
    __bf16* __restrict__ Yb, int* __restrict__ eidx, float* __restrict__ gate) {
  int wv = threadIdx.x >> 6, lane = threadIdx.x & 63;
  int t = blockIdx.x * 4 + wv;
  const float* xr = X + (size_t)t * D_;
  float4 xv[4];
  #pragma unroll
  for (int k = 0; k < 4; k++) xv[k] = *(const float4*)(xr + lane * 4 + k * 256);
  float s = 0.f;
  #pragma unroll
  for (int k = 0; k < 4; k++) s += xv[k].x + xv[k].y + xv[k].z + xv[k].w;
  float m = wave_sum(s) * (1.0f / D_);
  float vs = 0.f;
  #pragma unroll
  for (int k = 0; k < 4; k++) {
    float a = xv[k].x - m, b2 = xv[k].y - m, c = xv[k].z - m, d = xv[k].w - m;
    vs += a * a + b2 * b2 + c * c + d * d;
  }
  float rs = rsqrtf(wave_sum(vs) * (1.0f / D_) + 1e-5f);
  float y[4][4];
  #pragma unroll
  for (int k = 0; k < 4; k++) {
    int d0 = lane * 4 + k * 256;
    float4 wv4 = *(const float4*)(lw + d0);
    float4 bv4 = *(const float4*)(lb + d0);
    y[k][0] = (xv[k].x - m) * rs * wv4.x + bv4.x;
    y[k][1] = (xv[k].y - m) * rs * wv4.y + bv4.y;
    y[k][2] = (xv[k].z - m) * rs * wv4.z + bv4.z;
    y[k][3] = (xv[k].w - m) * rs * wv4.w + bv4.w;
    bf16x4 ob = {(__bf16)y[k][0], (__bf16)y[k][1], (__bf16)y[k][2], (__bf16)y[k][3]};
    *(bf16x4*)(Yb + (size_t)t * D_ + d0) = ob;
  }
  float g0 = 0, g1 = 0, g2 = 0, g3 = 0;
  #pragma unroll
  for (int k = 0; k < 4; k++)
    #pragma unroll
    for (int j = 0; j < 4; j++) {
      int d = lane * 4 + k * 256 + j;
      float4 gv = *(const float4*)(gw + (size_t)d * G_);
      float yv = y[k][j];
      g0 += yv * gv.x; g1 += yv * gv.y; g2 += yv * gv.z; g3 += yv * gv.w;
    }
  g0 = wave_sum(g0) + gb[0];
  g1 = wave_sum(g1) + gb[1];
  g2 = wave_sum(g2) + gb[2];
  g3 = wave_sum(g3) + gb[3];
  float mx = fmaxf(fmaxf(g0, g1), fmaxf(g2, g3));
  float p0 = __expf(g0 - mx), p1 = __expf(g1 - mx), p2 = __expf(g2 - mx), p3 = __expf(g3 - mx);
  float psum = p0 + p1 + p2 + p3;
  int gidx = 0; float best = g0;
  if (g1 > best) { best = g1; gidx = 1; }
  if (g2 > best) { best = g2; gidx = 2; }
  if (g3 > best) { best = g3; gidx = 3; }
  float gpsel = ((gidx == 0) ? p0 : (gidx == 1) ? p1 : (gidx == 2) ? p2 : p3) / psum;
  const float* ewg = ew + (size_t)gidx * D_ * EPG_;
  float e0 = 0, e1 = 0;
  #pragma unroll
  for (int k = 0; k < 4; k++)
    #pragma unroll
    for (int j = 0; j < 4; j++) {
      int d = lane * 4 + k * 256 + j;
      float2 ev = *(const float2*)(ewg + (size_t)d * EPG_);
      e0 += y[k][j] * ev.x; e1 += y[k][j] * ev.y;
    }
  e0 = wave_sum(e0) + eb[gidx * EPG_ + 0];
  e1 = wave_sum(e1) + eb[gidx * EPG_ + 1];
  float em = fmaxf(e0, e1);
  float q0 = __expf(e0 - em), q1 = __expf(e1 - em);
  int ei = (e1 > e0) ? 1 : 0;
  float epsel = ((ei == 0) ? q0 : q1) / (q0 + q1);
  if (lane == 0) {
    eidx[t] = gidx * EPG_ + ei;
    gate[t] = gpsel * epsel;
  }
}

// ---------------------------------------------------------------- finalize (64-row block list)
__global__ __launch_bounds__(256) void finalize_kernel(const int* __restrict__ eidx,
    int* __restrict__ counts, int* __restrict__ offs, int* __restrict__ tlist,
    int* __restrict__ blk) {
  __shared__ int hist[256][NE_];
  __shared__ int eoff[NE_];
  int tid = threadIdx.x;
  int loc[NE_];
  #pragma unroll
  for (int e = 0; e < NE_; e++) loc[e] = 0;
  int te[8];
  #pragma unroll
  for (int i = 0; i < 8; i++) { te[i] = eidx[tid * 8 + i]; loc[te[i]]++; }
  #pragma unroll
  for (int e = 0; e < NE_; e++) hist[tid][e] = loc[e];
  __syncthreads();
  for (int off = 1; off < 256; off <<= 1) {
    int v[NE_];
    #pragma unroll
    for (int e = 0; e < NE_; e++) v[e] = (tid >= off) ? hist[tid - off][e] : 0;
    __syncthreads();
    #pragma unroll
    for (int e = 0; e < NE_; e++) hist[tid][e] += v[e];
    __syncthreads();
  }
  if (tid == 0) {
    int acc = 0, nb = 0;
    for (int e = 0; e < NE_; e++) {
      int c = hist[255][e];
      eoff[e] = acc; counts[e] = c; offs[e] = acc; acc += c;
      for (int mt = 0; mt * 64 < c; mt++) blk[nb++] = e | (mt << 8);
    }
    for (; nb < MAXBLK_; nb++) blk[nb] = -1;
  }
  __syncthreads();
  int run[NE_];
  #pragma unroll
  for (int e = 0; e < NE_; e++) run[e] = eoff[e] + hist[tid][e] - loc[e];
  #pragma unroll
  for (int i = 0; i < 8; i++) {
    int e = te[i];
    tlist[run[e]++] = tid * 8 + i;
  }
}

// ---------------------------------------------------------------- bf16 MFMA GEMM (64-row tile, 2x2 waves)
// KN path B-staging: float4/float2 loads along N, extended XOR slot keeps
// writes/reads at the optimal 8-lanes-per-16B-slot balance.
// MODE 0: Cb = acc+bias (bf16)                       [qkv]
// MODE 1: Cf += acc+bias (f32 residual)              [out-proj]
// MODE 2: gather rows via tlist; Cb[compact] = relu  [moe w1]
// MODE 3: linear rows from compact; scatter to h     [moe w2]
template<int MODE, int NF, bool KN>
__global__ __launch_bounds__(256, 3) void gemm_mfma(
    const __bf16* __restrict__ A, const float* __restrict__ W,
    const float* __restrict__ bias, float* __restrict__ Cf,
    __bf16* __restrict__ Cb, const int* __restrict__ tlist,
    const int* __restrict__ offs, const int* __restrict__ counts,
    const float* __restrict__ gate, const int* __restrict__ blk,
    int N, int K) {
  __shared__ __bf16 As[2][64 * 64];
  __shared__ __bf16 Bs[2][NF * 32 * 64];
  int e = 0, mt = blockIdx.y, cnt = T_;
  if (MODE >= 2) {
    int bv = blk[blockIdx.y];
    if (bv < 0) return;
    e = bv & 255; mt = bv >> 8;
    cnt = counts[e];
  }
  int row0 = mt * 64;
  int lbase = (MODE >= 2) ? offs[e] : 0;
  int col0 = blockIdx.x * (NF * 32);
  const float* Wp = W + (size_t)e * N * K;
  const float* bp = bias + (size_t)e * N;
  int tid = threadIdx.x;
  int w = tid >> 6, lane = tid & 63, lq = lane & 15, lg = lane >> 4;
  int wr = w >> 1, wc = w & 1;

  const __bf16* asrc[2];
  #pragma unroll
  for (int it = 0; it < 2; it++) {
    int v = it * 256 + tid;
    int r = v >> 3, u = v & 7;
    int gr = row0 + r;
    long rowidx;
    if (MODE == 2) rowidx = tlist[lbase + ((gr < cnt) ? gr : cnt - 1)];
    else if (MODE == 3) rowidx = lbase + ((gr < cnt) ? gr : cnt - 1);
    else rowidx = gr;
    asrc[it] = A + (size_t)rowidx * K + (u ^ (r & 7)) * 8;
  }

  // --- B staging descriptors ---
  const float* bsrcNK[NF];
  int bdstNK[NF];
  const float* bbase = nullptr;   // KN vector-load base
  int wdst[NF];                   // KN write offsets (halfwords)
  int nq = tid & 31, kg = tid >> 5;   // KN mapping: kg in 0..7 (k-octet)
  if (KN) {
    bbase = Wp + (size_t)(kg * 8) * N + col0 + nq * NF;
    #pragma unroll
    for (int jj = 0; jj < NF; jj++) {
      int n = nq * NF + jj;
      int slot = (kg ^ (n & 7) ^ ((n >> 3) & 7)) & 7;
      wdst[jj] = n * 64 + slot * 8;
    }
  } else {
    #pragma unroll
    for (int it = 0; it < NF; it++) {
      int v = it * 256 + tid;
      int n = v >> 3, u = v & 7;
      bsrcNK[it] = Wp + (size_t)(col0 + n) * K + u * 8;
      bdstNK[it] = n * 64 + ((u ^ (n & 7) ^ ((n >> 3) & 7)) & 7) * 8;
    }
  }

  float brp[NF * 8];
  f32x4 acc[2][NF] = {};

  auto loadB = [&](int k0) {
    if (KN) {
      #pragma unroll
      for (int j = 0; j < 8; j++) {
        if (NF == 4) {
          float4 f = *(const float4*)(bbase + (size_t)(k0 + j) * N);
          brp[j * 4 + 0] = f.x; brp[j * 4 + 1] = f.y;
          brp[j * 4 + 2] = f.z; brp[j * 4 + 3] = f.w;
        } else {
          float2 f = *(const float2*)(bbase + (size_t)(k0 + j) * N);
          brp[j * 2 + 0] = f.x; brp[j * 2 + 1] = f.y;
        }
      }
    } else {
      #pragma unroll
      for (int it = 0; it < NF; it++) {
        float4 f0 = *(const float4*)(bsrcNK[it] + k0);
        float4 f1 = *(const float4*)(bsrcNK[it] + k0 + 4);
        brp[it * 8 + 0] = f0.x; brp[it * 8 + 1] = f0.y;
        brp[it * 8 + 2] = f0.z; brp[it * 8 + 3] = f0.w;
        brp[it * 8 + 4] = f1.x; brp[it * 8 + 5] = f1.y;
        brp[it * 8 + 6] = f1.z; brp[it * 8 + 7] = f1.w;
      }
    }
  };
  auto writeB = [&](int buf) {
    if (KN) {
      #pragma unroll
      for (int jj = 0; jj < NF; jj++) {
        bf16x8 bb = {(__bf16)brp[0 * NF + jj], (__bf16)brp[1 * NF + jj],
                     (__bf16)brp[2 * NF + jj], (__bf16)brp[3 * NF + jj],
                     (__bf16)brp[4 * NF + jj], (__bf16)brp[5 * NF + jj],
                     (__bf16)brp[6 * NF + jj], (__bf16)brp[7 * NF + jj]};
        *(bf16x8*)&Bs[buf][wdst[jj]] = bb;
      }
    } else {
      #pragma unroll
      for (int it = 0; it < NF; it++) {
        bf16x8 bb = {(__bf16)brp[it * 8 + 0], (__bf16)brp[it * 8 + 1],
                     (__bf16)brp[it * 8 + 2], (__bf16)brp[it * 8 + 3],
                     (__bf16)brp[it * 8 + 4], (__bf16)brp[it * 8 + 5],
                     (__bf16)brp[it * 8 + 6], (__bf16)brp[it * 8 + 7]};
        *(bf16x8*)&Bs[buf][bdstNK[it]] = bb;
      }
    }
  };
  auto stageA = [&](int buf, int k0) {
    #pragma unroll
    for (int it = 0; it < 2; it++)
      gl_lds16(asrc[it] + k0, &As[buf][(it * 256 + tid) * 8]);
  };
  auto mfmaPhase = [&](int buf) {
    __builtin_amdgcn_s_setprio(1);
    #pragma unroll
    for (int kk = 0; kk < 2; kk++) {
      bf16x8 a[2], b[NF];
      int usa = ((lg + kk * 4) ^ (lq & 7)) * 8;
      #pragma unroll
      for (int fi = 0; fi < 2; fi++)
        a[fi] = *(const bf16x8*)&As[buf][(wr * 32 + fi * 16 + lq) * 64 + usa];
      #pragma unroll
      for (int fj = 0; fj < NF; fj++) {
        int brow = wc * (NF * 16) + fj * 16 + lq;
        int usb = (((lg + kk * 4) ^ (brow & 7) ^ ((brow >> 3) & 7)) & 7) * 8;
        b[fj] = *(const bf16x8*)&Bs[buf][brow * 64 + usb];
      }
      #pragma unroll
      for (int fi = 0; fi < 2; fi++)
        #pragma unroll
        for (int fj = 0; fj < NF; fj++)
          acc[fi][fj] = __builtin_amdgcn_mfma_f32_16x16x32_bf16(a[fi], b[fj], acc[fi][fj], 0, 0, 0);
    }
    __builtin_amdgcn_s_setprio(0);
  };

  loadB(0);
  stageA(0, 0);
  writeB(0);
  __syncthreads();

  int buf = 0;
  for (int k0 = 0; k0 < K; k0 += 64) {
    int nk = k0 + 64;
    if (nk < K) {
      stageA(buf ^ 1, nk);
      loadB(nk);
    }
    mfmaPhase(buf);
    if (nk < K) writeB(buf ^ 1);
    __syncthreads();
    buf ^= 1;
  }

  #pragma unroll
  for (int fi = 0; fi < 2; fi++) {
    #pragma unroll
    for (int v = 0; v < 4; v++) {
      int r = row0 + wr * 32 + fi * 16 + lg * 4 + v;
      long orow;
      float gv = 1.f;
      if (MODE >= 2) {
        if (r >= cnt) continue;
        if (MODE == 2) orow = lbase + r;
        else { orow = tlist[lbase + r]; gv = gate[orow]; }
      } else {
        orow = r;
      }
      #pragma unroll
      for (int fj = 0; fj < NF; fj++) {
        int c = col0 + wc * (NF * 16) + fj * 16 + lq;
        float val = acc[fi][fj][v] + bp[c];
        if (MODE == 0)      Cb[orow * N + c] = (__bf16)val;
        else if (MODE == 1) Cf[orow * N + c] += val;
        else if (MODE == 2) Cb[orow * N + c] = (__bf16)fmaxf(val, 0.f);
        else                Cf[orow * N + c] += gv * val;
      }
    }
  }
}

// ---------------------------------------------------------------- flash attention, bf16 MFMA
// QB_=128, 512 thr = 8 waves. K/V double-buffered: stage(kt+1) issued before
// compute(kt) -> load latency hides under MFMA+softmax; 1 barrier per tile.
#define SC_LOG2 0.18033688011112042f   // (1/sqrt(64)) * log2(e)
__global__ __launch_bounds__(512) void attn_mfma_kernel(const __bf16* __restrict__ qkv,
                                                        __bf16* __restrict__ out) {
  __shared__ __bf16 Ks[2][64][72];
  __shared__ __bf16 Vt[2][64][72];  // [d][kv^swz]
  __shared__ __bf16 Ps[QB_][72];    // wave-private 16-row slabs
  int tid = threadIdx.x;
  int w = tid >> 6, lane = tid & 63, lq = lane & 15, lg = lane >> 4;
  int qt = (S_ / QB_ - 1) - blockIdx.x;   // heaviest first
  int b = blockIdx.y >> 4, hh = blockIdx.y & 15;
  const __bf16* qbase = qkv + (size_t)b * S_ * 3 * D_ + hh * HD_;

  bf16x8 qa[2];
  {
    const __bf16* qp = qbase + (size_t)(qt * QB_ + w * 16 + lq) * 3 * D_ + lg * 8;
    qa[0] = *(const bf16x8*)qp;
    qa[1] = *(const bf16x8*)(qp + 32);
  }

  f32x4 o[4] = {};
  float m_[4] = {-1e30f, -1e30f, -1e30f, -1e30f};
  float l_[4] = {0.f, 0.f, 0.f, 0.f};

  int rowmin = qt * QB_ + w * 16;       // first q-row this wave owns
  int srow = tid >> 3, sc8 = tid & 7;   // staging coords (512 thr cover 64x8)
  int nkt = qt * 2 + 2;

  auto stage = [&](int sb, int kt) {
    const __bf16* kp = qbase + (size_t)(kt * 64 + srow) * 3 * D_ + D_ + sc8 * 8;
    *(bf16x8*)&Ks[sb][srow][sc8 * 8] = *(const bf16x8*)kp;
    bf16x8 vv = *(const bf16x8*)(kp + D_);
    int cs = srow ^ (sc8 << 3);
    #pragma unroll
    for (int j = 0; j < 8; j++) Vt[sb][sc8 * 8 + j][cs] = vv[j];
  };

  stage(0, 0);
  __syncthreads();

  int buf = 0;
  for (int kt = 0; kt < nkt; kt++) {
    if (kt + 1 < nkt) stage(buf ^ 1, kt + 1);   // issue-early; writes land pre-barrier

    if (kt * 64 <= rowmin + 15) {       // wave active for this tile
      f32x4 s[4] = {};
      #pragma unroll
      for (int kk = 0; kk < 2; kk++)
        #pragma unroll
        for (int fc = 0; fc < 4; fc++) {
          bf16x8 kf = *(const bf16x8*)&Ks[buf][fc * 16 + lq][lg * 8 + kk * 32];
          s[fc] = __builtin_amdgcn_mfma_f32_16x16x32_bf16(qa[kk], kf, s[fc], 0, 0, 0);
        }

      bool need_mask = (kt * 64 + 63 > rowmin);
      #pragma unroll
      for (int fc = 0; fc < 4; fc++)
        #pragma unroll
        for (int v = 0; v < 4; v++) {
          float sv = s[fc][v] * SC_LOG2;
          if (need_mask && (kt * 64 + fc * 16 + lq) > (rowmin + lg * 4 + v)) sv = -1e30f;
          s[fc][v] = sv;
        }

      #pragma unroll
      for (int v = 0; v < 4; v++) {
        float rm = fmaxf(fmaxf(s[0][v], s[1][v]), fmaxf(s[2][v], s[3][v]));
        #pragma unroll
        for (int o2 = 8; o2 >= 1; o2 >>= 1) rm = fmaxf(rm, __shfl_xor(rm, o2, 64));
        if (rm > m_[v]) {   // rescale only when max grows (exact skip otherwise)
          float cc = exp2f(m_[v] - rm);
          m_[v] = rm;
          l_[v] *= cc;
          o[0][v] *= cc; o[1][v] *= cc; o[2][v] *= cc; o[3][v] *= cc;
        }
        float rs = 0.f;
        #pragma unroll
        for (int fc = 0; fc < 4; fc++) {
          float p = exp2f(s[fc][v] - m_[v]);
          s[fc][v] = p; rs += p;
        }
        l_[v] += rs;
        #pragma unroll
        for (int fc = 0; fc < 4; fc++)
          Ps[w * 16 + lg * 4 + v][fc * 16 + lq] = (__bf16)s[fc][v];
      }
      asm volatile("" ::: "memory");   // same-wave LDS FIFO: writes before reads

      #pragma unroll
      for (int kk = 0; kk < 2; kk++) {
        bf16x8 pa = *(const bf16x8*)&Ps[w * 16 + lq][lg * 8 + kk * 32];
        #pragma unroll
        for (int dc = 0; dc < 4; dc++) {
          int d = dc * 16 + lq;
          int col = (lg * 8 + kk * 32) ^ ((d >> 3) << 3);
          bf16x8 vb = *(const bf16x8*)&Vt[buf][d][col];
          o[dc] = __builtin_amdgcn_mfma_f32_16x16x32_bf16(pa, vb, o[dc], 0, 0, 0);
        }
      }
    }
    __syncthreads();   // joint: stage(buf^1) writes done AND compute(buf) reads done
    buf ^= 1;
  }

  #pragma unroll
  for (int v = 0; v < 4; v++) {
    float ls = l_[v];
    #pragma unroll
    for (int o2 = 8; o2 >= 1; o2 >>= 1) ls += __shfl_xor(ls, o2, 64);
    float inv = 1.0f / ls;
    int row = rowmin + lg * 4 + v;
    __bf16* op = out + ((size_t)b * S_ + row) * D_ + hh * HD_;
    #pragma unroll
    for (int dc = 0; dc < 4; dc++)
      op[dc * 16 + lq] = (__bf16)(o[dc][v] * inv);
  }
}

// ---------------------------------------------------------------- final mean + head (fp32)
__global__ __launch_bounds__(256) void mean_part_kernel(const float* __restrict__ X,
                                                        float* __restrict__ part) {
  int bd = blockIdx.x * 256 + threadIdx.x;
  int chunk = blockIdx.y;
  int b = bd >> 10, d = bd & 1023;
  float s = 0.f;
  #pragma unroll 4
  for (int i = 0; i < 64; i++) {
    int sidx = chunk * 64 + i;
    s += X[((size_t)b * S_ + sidx) * D_ + d];
  }
  part[chunk * T_ + bd] = s;
}

__global__ __launch_bounds__(256) void mean_final_kernel(const float* __restrict__ part,
                                                         float* __restrict__ hm) {
  int bd = blockIdx.x * 256 + threadIdx.x;
  float s = 0.f;
  #pragma unroll
  for (int c = 0; c < 16; c++) s += part[c * T_ + bd];
  hm[bd] = s * (1.0f / S_);
}

__global__ __launch_bounds__(256) void head_kernel(const float* __restrict__ hm,
    const float* __restrict__ hw, const float* __restrict__ hb,
    float* __restrict__ out) {
  int w = threadIdx.x >> 6;
  int lane = threadIdx.x & 63;
  int c = blockIdx.x * 4 + w;
  const float* row = hw + (size_t)c * D_;
  float acc0 = 0.f, acc1 = 0.f;
  #pragma unroll
  for (int k = 0; k < 4; k++) {
    int d = lane * 4 + k * 256;
    float4 wv = *(const float4*)(row + d);
    float4 h0 = *(const float4*)(hm + d);
    float4 h1 = *(const float4*)(hm + D_ + d);
    acc0 += wv.x * h0.x + wv.y * h0.y + wv.z * h0.z + wv.w * h0.w;
    acc1 += wv.x * h1.x + wv.y * h1.y + wv.z * h1.z + wv.w * h1.w;
  }
  #pragma unroll
  for (int o = 32; o >= 1; o >>= 1) {
    acc0 += __shfl_xor(acc0, o, 64);
    acc1 += __shfl_xor(acc1, o, 64);
  }
  if (lane == 0) {
    float bias = hb[c];
    out[c] = acc0 + bias;
    out[NC_ + c] = acc1 + bias;
  }
}

// ---------------------------------------------------------------- host launch
extern "C" void kernel_launch(void* const* d_in, const int* in_sizes, int n_in,
                              void* d_out, int out_size, void* d_ws, size_t ws_size,
                              hipStream_t stream) {
  const int*   x        = (const int*)d_in[0];
  const float* tok_emb  = (const float*)d_in[1];
  const float* pos_emb  = (const float*)d_in[2];
  const float* in_proj_w= (const float*)d_in[3];
  const float* in_proj_b= (const float*)d_in[4];
  const float* out_w    = (const float*)d_in[5];
  const float* out_b    = (const float*)d_in[6];
  const float* ln1_w    = (const float*)d_in[7];
  const float* ln1_b    = (const float*)d_in[8];
  const float* ln2_w    = (const float*)d_in[9];
  const float* ln2_b    = (const float*)d_in[10];
  const float* gr_w     = (const float*)d_in[11];
  const float* gr_b     = (const float*)d_in[12];
  const float* er_w     = (const float*)d_in[13];
  const float* er_b     = (const float*)d_in[14];
  const float* w1       = (const float*)d_in[15];
  const float* b1       = (const float*)d_in[16];
  const float* w2       = (const float*)d_in[17];
  const float* b2       = (const float*)d_in[18];
  const float* lnf_w    = (const float*)d_in[19];
  const float* lnf_b    = (const float*)d_in[20];
  const float* head_w   = (const float*)d_in[21];
  const float* head_b   = (const float*)d_in[22];

  char* wp = (char*)d_ws;
  auto carve = [&](size_t bytes) -> char* {
    char* p = wp;
    wp += (bytes + 255) & ~(size_t)255;
    return p;
  };
  float*  h      = (float*)carve((size_t)T_ * D_ * 4);
  float*  x1     = (float*)carve((size_t)T_ * D_ * 4);
  __bf16* x1b    = (__bf16*)carve((size_t)T_ * D_ * 2);
  __bf16* qkvb   = (__bf16*)carve((size_t)T_ * 3 * D_ * 2);
  __bf16* attnb  = (__bf16*)carve((size_t)T_ * D_ * 2);
  __bf16* hmidb  = (__bf16*)carve((size_t)T_ * H_ * 2);
  float*  part   = (float*)carve((size_t)16 * T_ * 4);
  float*  hm     = (float*)carve((size_t)B_ * D_ * 4);
  float*  gate   = (float*)carve((size_t)T_ * 4);
  int*    eidx   = (int*)carve((size_t)T_ * 4);
  int*    tlist  = (int*)carve((size_t)T_ * 4);
  int*    counts = (int*)carve(64);
  int*    offs   = (int*)carve(64);
  int*    blk    = (int*)carve(MAXBLK_ * 4);

  embed_kernel<<<T_, 256, 0, stream>>>(x, tok_emb, pos_emb, h);

  for (int l = 0; l < L_; l++) {
    // ---- attention half
    ln_kernel<false, true><<<T_, 256, 0, stream>>>(h, ln1_w + l * D_, ln1_b + l * D_,
                                                   nullptr, x1b);
    gemm_mfma<0, 4, false><<<dim3(24, 32, 1), 256, 0, stream>>>(
        x1b, in_proj_w + (size_t)l * 3 * D_ * D_, in_proj_b + (size_t)l * 3 * D_,
        nullptr, qkvb, nullptr, nullptr, nullptr, nullptr, nullptr, 3 * D_, D_);
    attn_mfma_kernel<<<dim3(S_ / QB_, B_ * NH_), 512, 0, stream>>>(qkvb, attnb);
    gemm_mfma<1, 2, false><<<dim3(16, 32, 1), 256, 0, stream>>>(
        attnb, out_w + (size_t)l * D_ * D_, out_b + (size_t)l * D_, h, nullptr,
        nullptr, nullptr, nullptr, nullptr, nullptr, D_, D_);

    // ---- MoE half (fused ln2 + route)
    ln_route_kernel<<<T_ / 4, 256, 0, stream>>>(h,
        ln2_w + l * D_, ln2_b + l * D_,
        gr_w + (size_t)l * D_ * G_, gr_b + (size_t)l * G_,
        er_w + (size_t)l * G_ * D_ * EPG_, er_b + (size_t)l * G_ * EPG_,
        x1b, eidx, gate);
    finalize_kernel<<<1, 256, 0, stream>>>(eidx, counts, offs, tlist, blk);

    gemm_mfma<2, 4, true><<<dim3(H_ / 128, MAXBLK_, 1), 256, 0, stream>>>(
        x1b, w1 + (size_t)l * NE_ * D_ * H_, b1 + (size_t)l * NE_ * H_, nullptr, hmidb,
        tlist, offs, counts, nullptr, blk, H_, D_);
    gemm_mfma<3, 2, true><<<dim3(D_ / 64, MAXBLK_, 1), 256, 0, stream>>>(
        hmidb, w2 + (size_t)l * NE_ * H_ * D_, b2 + (size_t)l * NE_ * D_, h, nullptr,
        tlist, offs, counts, gate, blk, D_, H_);
  }

  ln_kernel<true, false><<<T_, 256, 0, stream>>>(h, lnf_w, lnf_b, x1, nullptr);
  mean_part_kernel<<<dim3(B_ * D_ / 256, 16), 256, 0, stream>>>(x1, part);
  mean_final_kernel<<<B_ * D_ / 256, 256, 0, stream>>>(part, hm);
  head_kernel<<<NC_ / 4, 256, 0, stream>>>(hm, head_w, head_b, (float*)d_out);
}